// Round 3
// baseline (300.085 us; speedup 1.0000x reference)
//
#include <hip/hip_runtime.h>
#include <stdint.h>

// Pipeline: cvt(fp32->bf16) -> gemm_dp<0> QKV (deep-pipelined bf16 MFMA, scatter Q/K [BH][S][D], V^T [BH][D][S])
//           -> rope tables -> rope(Q,K, fold 1/sqrt(128) into Q)
//           -> causal flash attention (bf16 MFMA, paired q-blocks, dbuf)
//           -> gemm_dp<1>: out = Ao @ Wo^T (fp32 epilogue into d_out)
//
// gemm_dp: BM=128, BN=256, BK=32, 4-deep LDS ring (96KB), 8 waves (2M x 4N), counted vmcnt(6)
// schedule (T2+T3+T4+T5): phase kt = {ds_read frags buf[kt&3]; stage(kt+3); vmcnt(6); s_barrier;
// 16 MFMA setprio-wrapped; s_barrier}. Proof sketch: stage(k) lands before reads (drained by
// vmcnt at phase k-1 + barrier, 3-phase lookahead); stage(kt+3) overwrites slot of kt-1 whose
// reads finished before barrier2@kt-1. Raw s_barrier (NOT __syncthreads -> would vmcnt(0) drain).

#define SCALE_Q 0.08838834764831845f

typedef short bf16x8 __attribute__((ext_vector_type(8)));
typedef float f32x4 __attribute__((ext_vector_type(4)));
typedef unsigned short u16x4v __attribute__((ext_vector_type(4)));
typedef unsigned short u16x8v __attribute__((ext_vector_type(8)));

__device__ __forceinline__ unsigned short f2bf(float f) {
  unsigned u = __float_as_uint(f);
  return (unsigned short)((u + 0x7FFFu + ((u >> 16) & 1u)) >> 16);  // RNE
}
__device__ __forceinline__ float bf2f(unsigned short h) {
  return __uint_as_float(((unsigned)h) << 16);
}
__device__ __forceinline__ void gld16(void* lds, const void* g) {
  __builtin_amdgcn_global_load_lds(
      (const __attribute__((address_space(1))) unsigned int*)g,
      (__attribute__((address_space(3))) unsigned int*)lds, 16, 0, 0);
}

// ---------------- fp32 -> bf16 conversion (5 regions via blockIdx.y) ----------------
__global__ __launch_bounds__(256) void cvt_all(
    const float* __restrict__ x, const float* __restrict__ wq,
    const float* __restrict__ wk, const float* __restrict__ wv,
    const float* __restrict__ wo,
    unsigned short* __restrict__ xb, unsigned short* __restrict__ wqkv,
    unsigned short* __restrict__ wob) {
  int r = blockIdx.y;
  size_t i = ((size_t)blockIdx.x * 256 + threadIdx.x) * 8;
  const float* src; unsigned short* dst; size_t n;
  if (r == 0)      { src = x;  dst = xb;             n = 8388608; }
  else if (r == 1) { src = wq; dst = wqkv;           n = 4194304; }
  else if (r == 2) { src = wk; dst = wqkv + 4194304; n = 4194304; }
  else if (r == 3) { src = wv; dst = wqkv + 8388608; n = 4194304; }
  else             { src = wo; dst = wob;            n = 4194304; }
  if (i >= n) return;
  float4 a = *(const float4*)(src + i);
  float4 b = *(const float4*)(src + i + 4);
  u16x8v o;
  o[0] = f2bf(a.x); o[1] = f2bf(a.y); o[2] = f2bf(a.z); o[3] = f2bf(a.w);
  o[4] = f2bf(b.x); o[5] = f2bf(b.y); o[6] = f2bf(b.z); o[7] = f2bf(b.w);
  *(u16x8v*)(dst + i) = o;
}

// ---------------- RoPE tables ----------------
__global__ __launch_bounds__(256) void rope_table(float* __restrict__ ct, float* __restrict__ st) {
  int id = blockIdx.x * 256 + threadIdx.x;  // 131072 = 2048*64
  int s = id >> 6, j = id & 63;
  float inv = __powf(10000.0f, -(float)j * (1.0f / 64.0f));
  float a = (float)s * inv;
  ct[id] = __cosf(a);
  st[id] = __sinf(a);
}

// ---------------- deep-pipelined GEMM: C[M=.. x N] = A[M][K] @ B[N][K]^T ----------------
// BM=128 (rows, blockIdx-derived 'by'), BN=256, BK=32, 4-buffer ring, 512 threads (8 waves 2Mx4N).
// LDS per K-tile: A 8KB packed [64 ldsrows][128B] (ldsrow holds A-rows r and r+64),
//                 B 16KB packed [128 ldsrows][128B] (ldsrow holds B-rows r and r+128).
// 16B slot index (hi*4+g) XOR (ldsrow&7); staged linearly via gld16 with pre-swizzled source.
// MODE 0: scatter Q/K [BH][S][128], V^T [BH][128][S].  MODE 1: fp32 C0[row*N+col].
template <int MODE>
__global__ __launch_bounds__(512, 2) void gemm_dp(
    const unsigned short* __restrict__ A, const unsigned short* __restrict__ B,
    void* __restrict__ C0, void* __restrict__ C1, void* __restrict__ C2,
    int N, int Kd, int nbx) {
  __shared__ unsigned short As[4][64 * 64];    // 4 x 8KB
  __shared__ unsigned short Bs[4][128 * 64];   // 4 x 16KB
  const int t = threadIdx.x;
  const int lane = t & 63, w = t >> 6;
  const int g = lane >> 4, c15 = lane & 15;
  const int wm = w >> 2, wn = w & 3;

  // T1: bijective XCD swizzle (grid sizes are multiples of 8)
  const int nwg = (int)gridDim.x;
  const int swz = ((int)blockIdx.x & 7) * (nwg >> 3) + ((int)blockIdx.x >> 3);
  const int brow = (swz / nbx) * 128, bcol = (swz % nbx) * 256;

  // staging source pointers (pre-swizzled so linear LDS dest gets swizzled layout)
  const int arow = t >> 3;                       // 0..63
  const int alog = (t & 7) ^ (arow & 7);         // logical slot at phys slot t&7
  const unsigned short* srcA =
      A + (size_t)(brow + arow + (alog >> 2) * 64) * Kd + (alog & 3) * 8;
  const int blog = (t & 7) ^ ((t >> 3) & 7);
  const unsigned short* srcB =
      B + (size_t)(bcol + (t >> 3) + ((blog >> 2) << 7)) * Kd + (blog & 3) * 8;

  auto stage = [&](int kt) {
    const int buf = kt & 3;
    const unsigned short* a = srcA + kt * 32;
    const unsigned short* b = srcB + kt * 32;
    gld16((char*)As[buf] + t * 16, a);
    gld16((char*)Bs[buf] + t * 16, b);
    gld16((char*)Bs[buf] + 8192 + t * 16, b + (size_t)64 * Kd);
  };

  // fragment LDS byte offsets (2-way max bank aliasing, measured-0-conflict geometry)
  int aoff[4], boff[4];
#pragma unroll
  for (int mi = 0; mi < 4; ++mi)
    aoff[mi] = (mi * 16 + c15) * 128 + ((((wm << 2) | g) ^ (c15 & 7)) << 4);
#pragma unroll
  for (int nj = 0; nj < 4; ++nj) {
    int lr = ((wn & 1) << 6) + nj * 16 + c15;
    boff[nj] = lr * 128 + (((((wn >> 1) << 2) | g) ^ (c15 & 7)) << 4);
  }

  f32x4 zero4 = {0.f, 0.f, 0.f, 0.f};
  f32x4 acc[4][4];
#pragma unroll
  for (int a_ = 0; a_ < 4; ++a_)
#pragma unroll
    for (int b_ = 0; b_ < 4; ++b_) acc[a_][b_] = zero4;

  const int nk = Kd >> 5;  // 64
  stage(0); stage(1); stage(2);
  asm volatile("s_waitcnt vmcnt(6)" ::: "memory");
  __builtin_amdgcn_s_barrier();

  for (int kt = 0; kt < nk; ++kt) {
    const int buf = kt & 3;
    bf16x8 af[4], bfv[4];
#pragma unroll
    for (int mi = 0; mi < 4; ++mi)
      af[mi] = *(const bf16x8*)((const char*)As[buf] + aoff[mi]);
#pragma unroll
    for (int nj = 0; nj < 4; ++nj)
      bfv[nj] = *(const bf16x8*)((const char*)Bs[buf] + boff[nj]);
    if (kt + 3 < nk) {
      stage(kt + 3);
      asm volatile("s_waitcnt vmcnt(6)" ::: "memory");
    } else if (kt + 3 == nk) {
      asm volatile("s_waitcnt vmcnt(3)" ::: "memory");
    } else {
      asm volatile("s_waitcnt vmcnt(0)" ::: "memory");
    }
    __builtin_amdgcn_s_barrier();   // all waves: buf[kt] landed, reads may proceed next phase
    __builtin_amdgcn_s_setprio(1);
#pragma unroll
    for (int mi = 0; mi < 4; ++mi)
#pragma unroll
      for (int nj = 0; nj < 4; ++nj)
        acc[mi][nj] = __builtin_amdgcn_mfma_f32_16x16x32_bf16(
            af[mi], bfv[nj], acc[mi][nj], 0, 0, 0);
    __builtin_amdgcn_s_setprio(0);
    asm volatile("" ::: "memory");
    __builtin_amdgcn_s_barrier();   // all waves done reading buf[(kt-1)&3] slot before restage
  }

  // Epilogue. C/D layout: col = lane&15, row = (lane>>4)*4 + i  [m89]
#pragma unroll
  for (int mi = 0; mi < 4; ++mi) {
#pragma unroll
    for (int nj = 0; nj < 4; ++nj) {
      f32x4 v = acc[mi][nj];
      int row0 = brow + wm * 64 + mi * 16 + g * 4;
      int col = bcol + wn * 64 + nj * 16 + c15;
      if (MODE == 0) {
        int which = col >> 11;            // 0=Q 1=K 2=V
        int hc = col & 2047;
        int bh = ((row0 >> 11) << 4) + (hc >> 7);
        int d = hc & 127, s0 = row0 & 2047;
        if (which == 2) {                 // V^T: [bh][d][s], i-values are s-contiguous
          u16x4v pk;
          pk[0] = f2bf(v[0]); pk[1] = f2bf(v[1]); pk[2] = f2bf(v[2]); pk[3] = f2bf(v[3]);
          *(u16x4v*)((unsigned short*)C2 + ((size_t)bh * 128 + d) * 2048 + s0) = pk;
        } else {
          unsigned short* dst =
              (unsigned short*)(which ? C1 : C0) + ((size_t)bh * 2048 + s0) * 128 + d;
#pragma unroll
          for (int i = 0; i < 4; ++i) dst[(size_t)i * 128] = f2bf(v[i]);
        }
      } else {
        float* Cf = (float*)C0;
#pragma unroll
        for (int i = 0; i < 4; ++i) Cf[(size_t)(row0 + i) * N + col] = v[i];
      }
    }
  }
}

// ---------------- RoPE (in-place on bf16 Q,K [BH][S][128]); Q gets 1/sqrt(128) folded ----------------
__global__ __launch_bounds__(256) void rope_apply(
    unsigned short* __restrict__ Q, unsigned short* __restrict__ K,
    const float* __restrict__ ct, const float* __restrict__ st) {
  int id = blockIdx.x * 256 + threadIdx.x;  // 524288 = 32*2048*8
  int o = id & 7;
  int s = (id >> 3) & 2047;
  int bh = id >> 14;
  size_t base = ((size_t)bh * 2048 + s) * 128 + o * 8;
  u16x8v qlo = *(u16x8v*)(Q + base), qhi = *(u16x8v*)(Q + base + 64);
  u16x8v klo = *(u16x8v*)(K + base), khi = *(u16x8v*)(K + base + 64);
  const float* cp = ct + s * 64 + o * 8;
  const float* sp = st + s * 64 + o * 8;
#pragma unroll
  for (int j = 0; j < 8; ++j) {
    float c = cp[j], sn = sp[j];
    float ql = bf2f(qlo[j]), qh = bf2f(qhi[j]);
    qlo[j] = f2bf((ql * c - qh * sn) * SCALE_Q);
    qhi[j] = f2bf((qh * c + ql * sn) * SCALE_Q);
    float kl = bf2f(klo[j]), kh = bf2f(khi[j]);
    klo[j] = f2bf(kl * c - kh * sn);
    khi[j] = f2bf(kh * c + kl * sn);
  }
  *(u16x8v*)(Q + base) = qlo; *(u16x8v*)(Q + base + 64) = qhi;
  *(u16x8v*)(K + base) = klo; *(u16x8v*)(K + base + 64) = khi;
}

// ---------------- causal flash attention: paired q-blocks + dbuf K/V (unchanged from R2) ----------------
__global__ __launch_bounds__(256) void attn_fwd(
    const unsigned short* __restrict__ Qg, const unsigned short* __restrict__ Kg,
    const unsigned short* __restrict__ Vtg, unsigned short* __restrict__ Og) {
  __shared__ unsigned short Ks[2][64 * 128];
  __shared__ unsigned short Vs[2][64 * 128];
  __shared__ unsigned short Pl[4][16 * 88];
  const int t = threadIdx.x;
  const int lane = t & 63, w = t >> 6;
  const int g = lane >> 4, c15 = lane & 15;
  const int pair = blockIdx.x;
  const int bh = blockIdx.y;
  const int b = bh >> 4, h = bh & 15;

  const int ksrow = t >> 4;
  const int kssl = (t & 15) ^ ksrow;
  const unsigned short* kp = Kg + ((size_t)bh * 2048 + ksrow) * 128 + kssl * 8;
  const int vsrow = t >> 3;
  const int vssl = (t & 7) ^ (vsrow & 7);
  const unsigned short* vp = Vtg + ((size_t)bh * 128 + vsrow) * 2048 + vssl * 8;

  auto stageTile = [&](int buf, int tkv) {
#pragma unroll
    for (int c = 0; c < 4; ++c) {
      gld16((char*)Ks[buf] + c * 4096 + t * 16, kp + (size_t)(tkv * 64 + c * 16) * 128);
      gld16((char*)Vs[buf] + c * 4096 + t * 16, vp + (size_t)c * 32 * 2048 + tkv * 64);
    }
  };

  f32x4 zero4 = {0.f, 0.f, 0.f, 0.f};
  f32x4 o[8];
  float mrow[4], lrow[4];
  bf16x8 qf[4];

  auto computeTile = [&](int buf, int qb, int tkv) {
    const int q0 = qb * 64;
    const int qrow = q0 + w * 16;
    f32x4 sv[4];
    __builtin_amdgcn_s_setprio(1);
#pragma unroll
    for (int cb = 0; cb < 4; ++cb) {
      f32x4 z = zero4;
#pragma unroll
      for (int kf = 0; kf < 4; ++kf) {
        int row = cb * 16 + c15;
        int p = (kf * 4 + g) ^ c15;
        bf16x8 kfr = *(const bf16x8*)((const char*)Ks[buf] + row * 256 + p * 16);
        z = __builtin_amdgcn_mfma_f32_16x16x32_bf16(qf[kf], kfr, z, 0, 0, 0);
      }
      sv[cb] = z;
    }
    __builtin_amdgcn_s_setprio(0);
    if (tkv == qb) {
#pragma unroll
      for (int cb = 0; cb < 4; ++cb)
#pragma unroll
        for (int i = 0; i < 4; ++i) {
          int colk = q0 + cb * 16 + c15;
          int rq = qrow + g * 4 + i;
          if (colk > rq) sv[cb][i] = -1e30f;
        }
    }
    float pmx[4];
#pragma unroll
    for (int i = 0; i < 4; ++i)
      pmx[i] = fmaxf(fmaxf(sv[0][i], sv[1][i]), fmaxf(sv[2][i], sv[3][i]));
#pragma unroll
    for (int dd = 1; dd < 16; dd <<= 1)
#pragma unroll
      for (int i = 0; i < 4; ++i) pmx[i] = fmaxf(pmx[i], __shfl_xor(pmx[i], dd));
    float sc[4], psum[4];
#pragma unroll
    for (int i = 0; i < 4; ++i) {
      float nm = fmaxf(mrow[i], pmx[i]);
      sc[i] = __expf(mrow[i] - nm);
      mrow[i] = nm;
      psum[i] = 0.f;
    }
#pragma unroll
    for (int cb = 0; cb < 4; ++cb)
#pragma unroll
      for (int i = 0; i < 4; ++i) {
        float e = __expf(sv[cb][i] - mrow[i]);
        sv[cb][i] = e;
        psum[i] += e;
      }
#pragma unroll
    for (int dd = 1; dd < 16; dd <<= 1)
#pragma unroll
      for (int i = 0; i < 4; ++i) psum[i] += __shfl_xor(psum[i], dd);
#pragma unroll
    for (int i = 0; i < 4; ++i) lrow[i] = lrow[i] * sc[i] + psum[i];
#pragma unroll
    for (int db = 0; db < 8; ++db)
#pragma unroll
      for (int i = 0; i < 4; ++i) o[db][i] *= sc[i];

    unsigned short* pw = &Pl[w][0];
#pragma unroll
    for (int cb = 0; cb < 4; ++cb)
#pragma unroll
      for (int i = 0; i < 4; ++i)
        pw[(g * 4 + i) * 88 + cb * 16 + c15] = f2bf(sv[cb][i]);
    bf16x8 pf[2];
#pragma unroll
    for (int kb = 0; kb < 2; ++kb)
      pf[kb] = *(const bf16x8*)((const char*)pw + c15 * 176 + kb * 64 + g * 16);

    __builtin_amdgcn_s_setprio(1);
#pragma unroll
    for (int db = 0; db < 8; ++db) {
#pragma unroll
      for (int kb = 0; kb < 2; ++kb) {
        int row = db * 16 + c15;
        int p = (kb * 4 + g) ^ (c15 & 7);
        bf16x8 vfr = *(const bf16x8*)((const char*)Vs[buf] + row * 128 + p * 16);
        o[db] = __builtin_amdgcn_mfma_f32_16x16x32_bf16(pf[kb], vfr, o[db], 0, 0, 0);
      }
    }
    __builtin_amdgcn_s_setprio(0);
  };

  auto loadQ = [&](int qb) {
    const unsigned short* qp = Qg + ((size_t)bh * 2048 + qb * 64 + w * 16 + c15) * 128 + g * 8;
#pragma unroll
    for (int kf = 0; kf < 4; ++kf) qf[kf] = *(const bf16x8*)(qp + kf * 32);
#pragma unroll
    for (int db = 0; db < 8; ++db) o[db] = zero4;
#pragma unroll
    for (int i = 0; i < 4; ++i) { mrow[i] = -1e30f; lrow[i] = 0.f; }
  };

  auto writeO = [&](int qb) {
    float linv[4];
#pragma unroll
    for (int i = 0; i < 4; ++i) linv[i] = 1.0f / lrow[i];
#pragma unroll
    for (int db = 0; db < 8; ++db)
#pragma unroll
      for (int i = 0; i < 4; ++i) {
        int q = qb * 64 + w * 16 + g * 4 + i;
        Og[((size_t)(b * 2048 + q)) * 2048 + h * 128 + db * 16 + c15] =
            f2bf(o[db][i] * linv[i]);
      }
  };

  const int qbA = pair, qbB = 31 - pair;
  const int ntA = qbA + 1, ntB = qbB + 1;
  int cur = 0;

  stageTile(0, 0);
  loadQ(qbA);
  for (int tkv = 0; tkv < ntA; ++tkv) {
    __syncthreads();
    if (tkv + 1 < ntA) stageTile(cur ^ 1, tkv + 1);
    else               stageTile(cur ^ 1, 0);
    computeTile(cur, qbA, tkv);
    cur ^= 1;
  }
  writeO(qbA);
  loadQ(qbB);
  for (int tkv = 0; tkv < ntB; ++tkv) {
    __syncthreads();
    if (tkv + 1 < ntB) stageTile(cur ^ 1, tkv + 1);
    computeTile(cur, qbB, tkv);
    cur ^= 1;
  }
  writeO(qbB);
}

extern "C" void kernel_launch(void* const* d_in, const int* in_sizes, int n_in,
                              void* d_out, int out_size, void* d_ws, size_t ws_size,
                              hipStream_t stream) {
  const float* x  = (const float*)d_in[0];
  const float* Wq = (const float*)d_in[1];
  const float* Wk = (const float*)d_in[2];
  const float* Wv = (const float*)d_in[3];
  const float* Wo = (const float*)d_in[4];
  char* p = (char*)d_ws;
  unsigned short* xb    = (unsigned short*)p;                 // 16 MB (reused as Ao)
  unsigned short* wqkvb = (unsigned short*)(p + 16777216);    // 24 MB
  unsigned short* wob   = (unsigned short*)(p + 41943040);    //  8 MB
  unsigned short* Qb    = (unsigned short*)(p + 50331648);    // 16 MB
  unsigned short* Kb    = (unsigned short*)(p + 67108864);    // 16 MB
  unsigned short* Vt    = (unsigned short*)(p + 83886080);    // 16 MB
  float* ctab           = (float*)(p + 100663296);            // 0.5 MB
  float* stab           = (float*)(p + 101187584);            // 0.5 MB -> end 101711872
  unsigned short* Ao = xb;  // xb dead after gemm_qkv

  cvt_all<<<dim3(4096, 5), 256, 0, stream>>>(x, Wq, Wk, Wv, Wo, xb, wqkvb, wob);
  rope_table<<<512, 256, 0, stream>>>(ctab, stab);
  gemm_dp<0><<<768, 512, 0, stream>>>(xb, wqkvb, Qb, Kb, Vt, 6144, 2048, 24);
  rope_apply<<<2048, 256, 0, stream>>>(Qb, Kb, ctab, stab);
  attn_fwd<<<dim3(16, 32), 256, 0, stream>>>(Qb, Kb, Vt, Ao);
  gemm_dp<1><<<256, 512, 0, stream>>>(Ao, wob, d_out, nullptr, nullptr, 2048, 2048, 8);
}

// Round 4
// 293.010 us; speedup vs baseline: 1.0241x; 1.0241x over previous
//
#include <hip/hip_runtime.h>
#include <stdint.h>

// Pipeline: cvt(fp32->bf16) -> gemm_dp<0> QKV (deep-pipelined bf16 MFMA, scatter Q/K [BH][S][D], V^T [BH][D][S])
//           -> rope tables -> rope(Q,K, fold 1/sqrt(128) into Q)
//           -> causal flash attention (bf16 MFMA, paired q-blocks, dbuf)
//           -> gemm_dp<1>: out = Ao @ Wo^T (fp32 epilogue into d_out)
//
// gemm_dp: BM=128, BN=256, BK=32, 4-deep LDS ring (96KB), 8 waves (2M x 4N), counted vmcnt(6).
// R4: 2-D XCD chunking — each XCD owns 16 row-tiles x (nbx/4) col-tiles, col-major within
// chunk so the 32 co-resident blocks = 16 rows x 2 cols -> per-phase L2 fill 160KB/XCD
// (R3's 1-D map gave 4 rows x all cols = 400KB/XCD -> FETCH 307MB, fill-bound at 2.1TB/s).

#define SCALE_Q 0.08838834764831845f

typedef short bf16x8 __attribute__((ext_vector_type(8)));
typedef float f32x4 __attribute__((ext_vector_type(4)));
typedef unsigned short u16x4v __attribute__((ext_vector_type(4)));
typedef unsigned short u16x8v __attribute__((ext_vector_type(8)));

__device__ __forceinline__ unsigned short f2bf(float f) {
  unsigned u = __float_as_uint(f);
  return (unsigned short)((u + 0x7FFFu + ((u >> 16) & 1u)) >> 16);  // RNE
}
__device__ __forceinline__ float bf2f(unsigned short h) {
  return __uint_as_float(((unsigned)h) << 16);
}
__device__ __forceinline__ void gld16(void* lds, const void* g) {
  __builtin_amdgcn_global_load_lds(
      (const __attribute__((address_space(1))) unsigned int*)g,
      (__attribute__((address_space(3))) unsigned int*)lds, 16, 0, 0);
}

// ---------------- fp32 -> bf16 conversion (5 regions via blockIdx.y) ----------------
__global__ __launch_bounds__(256) void cvt_all(
    const float* __restrict__ x, const float* __restrict__ wq,
    const float* __restrict__ wk, const float* __restrict__ wv,
    const float* __restrict__ wo,
    unsigned short* __restrict__ xb, unsigned short* __restrict__ wqkv,
    unsigned short* __restrict__ wob) {
  int r = blockIdx.y;
  size_t i = ((size_t)blockIdx.x * 256 + threadIdx.x) * 8;
  const float* src; unsigned short* dst; size_t n;
  if (r == 0)      { src = x;  dst = xb;             n = 8388608; }
  else if (r == 1) { src = wq; dst = wqkv;           n = 4194304; }
  else if (r == 2) { src = wk; dst = wqkv + 4194304; n = 4194304; }
  else if (r == 3) { src = wv; dst = wqkv + 8388608; n = 4194304; }
  else             { src = wo; dst = wob;            n = 4194304; }
  if (i >= n) return;
  float4 a = *(const float4*)(src + i);
  float4 b = *(const float4*)(src + i + 4);
  u16x8v o;
  o[0] = f2bf(a.x); o[1] = f2bf(a.y); o[2] = f2bf(a.z); o[3] = f2bf(a.w);
  o[4] = f2bf(b.x); o[5] = f2bf(b.y); o[6] = f2bf(b.z); o[7] = f2bf(b.w);
  *(u16x8v*)(dst + i) = o;
}

// ---------------- RoPE tables ----------------
__global__ __launch_bounds__(256) void rope_table(float* __restrict__ ct, float* __restrict__ st) {
  int id = blockIdx.x * 256 + threadIdx.x;  // 131072 = 2048*64
  int s = id >> 6, j = id & 63;
  float inv = __powf(10000.0f, -(float)j * (1.0f / 64.0f));
  float a = (float)s * inv;
  ct[id] = __cosf(a);
  st[id] = __sinf(a);
}

// ---------------- deep-pipelined GEMM: C = A[M][K] @ B[N][K]^T ----------------
// BM=128, BN=256, BK=32, 4-buffer ring, 512 threads (8 waves 2Mx4N).
// Grid must be 32 row-tiles x nbx col-tiles, nbx % 4 == 0, nwg = 32*nbx.
// MODE 0: scatter Q/K [BH][S][128], V^T [BH][128][S].  MODE 1: fp32 C0[row*N+col].
template <int MODE>
__global__ __launch_bounds__(512, 2) void gemm_dp(
    const unsigned short* __restrict__ A, const unsigned short* __restrict__ B,
    void* __restrict__ C0, void* __restrict__ C1, void* __restrict__ C2,
    int N, int Kd, int nbx) {
  __shared__ unsigned short As[4][64 * 64];    // 4 x 8KB
  __shared__ unsigned short Bs[4][128 * 64];   // 4 x 16KB
  const int t = threadIdx.x;
  const int lane = t & 63, w = t >> 6;
  const int g = lane >> 4, c15 = lane & 15;
  const int wm = w >> 2, wn = w & 3;

  // T1 + 2-D chunking: XCD = blockIdx.x % 8 owns chunk of 16 rows x (nbx/4) cols,
  // col-major within chunk (co-resident 32 blocks span 16 rows x 2 cols).
  const int nwg = (int)gridDim.x;
  const int cpx = nwg >> 3;                                  // blocks per chunk (96 / 32)
  const int chunk = (int)blockIdx.x & 7;
  const int idx = (int)blockIdx.x >> 3;                      // 0..cpx-1, sliding window
  const int cpc = nbx >> 2;                                  // cols per chunk
  const int row = (chunk >> 2) * 16 + (idx & 15);
  const int col = (chunk & 3) * cpc + (idx >> 4);
  const int brow = row * 128, bcol = col * 256;

  // staging source pointers (pre-swizzled so linear LDS dest gets swizzled layout)
  const int arow = t >> 3;                       // 0..63
  const int alog = (t & 7) ^ (arow & 7);         // logical slot at phys slot t&7
  const unsigned short* srcA =
      A + (size_t)(brow + arow + (alog >> 2) * 64) * Kd + (alog & 3) * 8;
  const int blog = (t & 7) ^ ((t >> 3) & 7);
  const unsigned short* srcB =
      B + (size_t)(bcol + (t >> 3) + ((blog >> 2) << 7)) * Kd + (blog & 3) * 8;

  auto stage = [&](int kt) {
    const int buf = kt & 3;
    const unsigned short* a = srcA + kt * 32;
    const unsigned short* b = srcB + kt * 32;
    gld16((char*)As[buf] + t * 16, a);
    gld16((char*)Bs[buf] + t * 16, b);
    gld16((char*)Bs[buf] + 8192 + t * 16, b + (size_t)64 * Kd);
  };

  // fragment LDS byte offsets (2-way max bank aliasing, measured-0-conflict geometry)
  int aoff[4], boff[4];
#pragma unroll
  for (int mi = 0; mi < 4; ++mi)
    aoff[mi] = (mi * 16 + c15) * 128 + ((((wm << 2) | g) ^ (c15 & 7)) << 4);
#pragma unroll
  for (int nj = 0; nj < 4; ++nj) {
    int lr = ((wn & 1) << 6) + nj * 16 + c15;
    boff[nj] = lr * 128 + (((((wn >> 1) << 2) | g) ^ (c15 & 7)) << 4);
  }

  f32x4 zero4 = {0.f, 0.f, 0.f, 0.f};
  f32x4 acc[4][4];
#pragma unroll
  for (int a_ = 0; a_ < 4; ++a_)
#pragma unroll
    for (int b_ = 0; b_ < 4; ++b_) acc[a_][b_] = zero4;

  const int nk = Kd >> 5;  // 64
  stage(0); stage(1); stage(2);
  asm volatile("s_waitcnt vmcnt(6)" ::: "memory");
  __builtin_amdgcn_s_barrier();

  for (int kt = 0; kt < nk; ++kt) {
    const int buf = kt & 3;
    bf16x8 af[4], bfv[4];
#pragma unroll
    for (int mi = 0; mi < 4; ++mi)
      af[mi] = *(const bf16x8*)((const char*)As[buf] + aoff[mi]);
#pragma unroll
    for (int nj = 0; nj < 4; ++nj)
      bfv[nj] = *(const bf16x8*)((const char*)Bs[buf] + boff[nj]);
    if (kt + 3 < nk) {
      stage(kt + 3);
      asm volatile("s_waitcnt vmcnt(6)" ::: "memory");
    } else if (kt + 3 == nk) {
      asm volatile("s_waitcnt vmcnt(3)" ::: "memory");
    } else {
      asm volatile("s_waitcnt vmcnt(0)" ::: "memory");
    }
    __builtin_amdgcn_s_barrier();   // all waves: buf[kt] landed, reads may proceed next phase
    __builtin_amdgcn_s_setprio(1);
#pragma unroll
    for (int mi = 0; mi < 4; ++mi)
#pragma unroll
      for (int nj = 0; nj < 4; ++nj)
        acc[mi][nj] = __builtin_amdgcn_mfma_f32_16x16x32_bf16(
            af[mi], bfv[nj], acc[mi][nj], 0, 0, 0);
    __builtin_amdgcn_s_setprio(0);
    asm volatile("" ::: "memory");
    __builtin_amdgcn_s_barrier();   // all waves done reading old slot before restage
  }

  // Epilogue. C/D layout: col = lane&15, row = (lane>>4)*4 + i  [m89]
#pragma unroll
  for (int mi = 0; mi < 4; ++mi) {
#pragma unroll
    for (int nj = 0; nj < 4; ++nj) {
      f32x4 v = acc[mi][nj];
      int row0 = brow + wm * 64 + mi * 16 + g * 4;
      int colc = bcol + wn * 64 + nj * 16 + c15;
      if (MODE == 0) {
        int which = colc >> 11;           // 0=Q 1=K 2=V
        int hc = colc & 2047;
        int bh = ((row0 >> 11) << 4) + (hc >> 7);
        int d = hc & 127, s0 = row0 & 2047;
        if (which == 2) {                 // V^T: [bh][d][s], i-values are s-contiguous
          u16x4v pk;
          pk[0] = f2bf(v[0]); pk[1] = f2bf(v[1]); pk[2] = f2bf(v[2]); pk[3] = f2bf(v[3]);
          *(u16x4v*)((unsigned short*)C2 + ((size_t)bh * 128 + d) * 2048 + s0) = pk;
        } else {
          unsigned short* dst =
              (unsigned short*)(which ? C1 : C0) + ((size_t)bh * 2048 + s0) * 128 + d;
#pragma unroll
          for (int i = 0; i < 4; ++i) dst[(size_t)i * 128] = f2bf(v[i]);
        }
      } else {
        float* Cf = (float*)C0;
#pragma unroll
        for (int i = 0; i < 4; ++i) Cf[(size_t)(row0 + i) * N + colc] = v[i];
      }
    }
  }
}

// ---------------- RoPE (in-place on bf16 Q,K [BH][S][128]); Q gets 1/sqrt(128) folded ----------------
__global__ __launch_bounds__(256) void rope_apply(
    unsigned short* __restrict__ Q, unsigned short* __restrict__ K,
    const float* __restrict__ ct, const float* __restrict__ st) {
  int id = blockIdx.x * 256 + threadIdx.x;  // 524288 = 32*2048*8
  int o = id & 7;
  int s = (id >> 3) & 2047;
  int bh = id >> 14;
  size_t base = ((size_t)bh * 2048 + s) * 128 + o * 8;
  u16x8v qlo = *(u16x8v*)(Q + base), qhi = *(u16x8v*)(Q + base + 64);
  u16x8v klo = *(u16x8v*)(K + base), khi = *(u16x8v*)(K + base + 64);
  const float* cp = ct + s * 64 + o * 8;
  const float* sp = st + s * 64 + o * 8;
#pragma unroll
  for (int j = 0; j < 8; ++j) {
    float c = cp[j], sn = sp[j];
    float ql = bf2f(qlo[j]), qh = bf2f(qhi[j]);
    qlo[j] = f2bf((ql * c - qh * sn) * SCALE_Q);
    qhi[j] = f2bf((qh * c + ql * sn) * SCALE_Q);
    float kl = bf2f(klo[j]), kh = bf2f(khi[j]);
    klo[j] = f2bf(kl * c - kh * sn);
    khi[j] = f2bf(kh * c + kl * sn);
  }
  *(u16x8v*)(Q + base) = qlo; *(u16x8v*)(Q + base + 64) = qhi;
  *(u16x8v*)(K + base) = klo; *(u16x8v*)(K + base + 64) = khi;
}

// ---------------- causal flash attention: paired q-blocks + dbuf K/V (unchanged) ----------------
__global__ __launch_bounds__(256) void attn_fwd(
    const unsigned short* __restrict__ Qg, const unsigned short* __restrict__ Kg,
    const unsigned short* __restrict__ Vtg, unsigned short* __restrict__ Og) {
  __shared__ unsigned short Ks[2][64 * 128];
  __shared__ unsigned short Vs[2][64 * 128];
  __shared__ unsigned short Pl[4][16 * 88];
  const int t = threadIdx.x;
  const int lane = t & 63, w = t >> 6;
  const int g = lane >> 4, c15 = lane & 15;
  const int pair = blockIdx.x;
  const int bh = blockIdx.y;
  const int b = bh >> 4, h = bh & 15;

  const int ksrow = t >> 4;
  const int kssl = (t & 15) ^ ksrow;
  const unsigned short* kp = Kg + ((size_t)bh * 2048 + ksrow) * 128 + kssl * 8;
  const int vsrow = t >> 3;
  const int vssl = (t & 7) ^ (vsrow & 7);
  const unsigned short* vp = Vtg + ((size_t)bh * 128 + vsrow) * 2048 + vssl * 8;

  auto stageTile = [&](int buf, int tkv) {
#pragma unroll
    for (int c = 0; c < 4; ++c) {
      gld16((char*)Ks[buf] + c * 4096 + t * 16, kp + (size_t)(tkv * 64 + c * 16) * 128);
      gld16((char*)Vs[buf] + c * 4096 + t * 16, vp + (size_t)c * 32 * 2048 + tkv * 64);
    }
  };

  f32x4 zero4 = {0.f, 0.f, 0.f, 0.f};
  f32x4 o[8];
  float mrow[4], lrow[4];
  bf16x8 qf[4];

  auto computeTile = [&](int buf, int qb, int tkv) {
    const int q0 = qb * 64;
    const int qrow = q0 + w * 16;
    f32x4 sv[4];
    __builtin_amdgcn_s_setprio(1);
#pragma unroll
    for (int cb = 0; cb < 4; ++cb) {
      f32x4 z = zero4;
#pragma unroll
      for (int kf = 0; kf < 4; ++kf) {
        int row = cb * 16 + c15;
        int p = (kf * 4 + g) ^ c15;
        bf16x8 kfr = *(const bf16x8*)((const char*)Ks[buf] + row * 256 + p * 16);
        z = __builtin_amdgcn_mfma_f32_16x16x32_bf16(qf[kf], kfr, z, 0, 0, 0);
      }
      sv[cb] = z;
    }
    __builtin_amdgcn_s_setprio(0);
    if (tkv == qb) {
#pragma unroll
      for (int cb = 0; cb < 4; ++cb)
#pragma unroll
        for (int i = 0; i < 4; ++i) {
          int colk = q0 + cb * 16 + c15;
          int rq = qrow + g * 4 + i;
          if (colk > rq) sv[cb][i] = -1e30f;
        }
    }
    float pmx[4];
#pragma unroll
    for (int i = 0; i < 4; ++i)
      pmx[i] = fmaxf(fmaxf(sv[0][i], sv[1][i]), fmaxf(sv[2][i], sv[3][i]));
#pragma unroll
    for (int dd = 1; dd < 16; dd <<= 1)
#pragma unroll
      for (int i = 0; i < 4; ++i) pmx[i] = fmaxf(pmx[i], __shfl_xor(pmx[i], dd));
    float sc[4], psum[4];
#pragma unroll
    for (int i = 0; i < 4; ++i) {
      float nm = fmaxf(mrow[i], pmx[i]);
      sc[i] = __expf(mrow[i] - nm);
      mrow[i] = nm;
      psum[i] = 0.f;
    }
#pragma unroll
    for (int cb = 0; cb < 4; ++cb)
#pragma unroll
      for (int i = 0; i < 4; ++i) {
        float e = __expf(sv[cb][i] - mrow[i]);
        sv[cb][i] = e;
        psum[i] += e;
      }
#pragma unroll
    for (int dd = 1; dd < 16; dd <<= 1)
#pragma unroll
      for (int i = 0; i < 4; ++i) psum[i] += __shfl_xor(psum[i], dd);
#pragma unroll
    for (int i = 0; i < 4; ++i) lrow[i] = lrow[i] * sc[i] + psum[i];
#pragma unroll
    for (int db = 0; db < 8; ++db)
#pragma unroll
      for (int i = 0; i < 4; ++i) o[db][i] *= sc[i];

    unsigned short* pw = &Pl[w][0];
#pragma unroll
    for (int cb = 0; cb < 4; ++cb)
#pragma unroll
      for (int i = 0; i < 4; ++i)
        pw[(g * 4 + i) * 88 + cb * 16 + c15] = f2bf(sv[cb][i]);
    bf16x8 pf[2];
#pragma unroll
    for (int kb = 0; kb < 2; ++kb)
      pf[kb] = *(const bf16x8*)((const char*)pw + c15 * 176 + kb * 64 + g * 16);

    __builtin_amdgcn_s_setprio(1);
#pragma unroll
    for (int db = 0; db < 8; ++db) {
#pragma unroll
      for (int kb = 0; kb < 2; ++kb) {
        int row = db * 16 + c15;
        int p = (kb * 4 + g) ^ (c15 & 7);
        bf16x8 vfr = *(const bf16x8*)((const char*)Vs[buf] + row * 128 + p * 16);
        o[db] = __builtin_amdgcn_mfma_f32_16x16x32_bf16(pf[kb], vfr, o[db], 0, 0, 0);
      }
    }
    __builtin_amdgcn_s_setprio(0);
  };

  auto loadQ = [&](int qb) {
    const unsigned short* qp = Qg + ((size_t)bh * 2048 + qb * 64 + w * 16 + c15) * 128 + g * 8;
#pragma unroll
    for (int kf = 0; kf < 4; ++kf) qf[kf] = *(const bf16x8*)(qp + kf * 32);
#pragma unroll
    for (int db = 0; db < 8; ++db) o[db] = zero4;
#pragma unroll
    for (int i = 0; i < 4; ++i) { mrow[i] = -1e30f; lrow[i] = 0.f; }
  };

  auto writeO = [&](int qb) {
    float linv[4];
#pragma unroll
    for (int i = 0; i < 4; ++i) linv[i] = 1.0f / lrow[i];
#pragma unroll
    for (int db = 0; db < 8; ++db)
#pragma unroll
      for (int i = 0; i < 4; ++i) {
        int q = qb * 64 + w * 16 + g * 4 + i;
        Og[((size_t)(b * 2048 + q)) * 2048 + h * 128 + db * 16 + c15] =
            f2bf(o[db][i] * linv[i]);
      }
  };

  const int qbA = pair, qbB = 31 - pair;
  const int ntA = qbA + 1, ntB = qbB + 1;
  int cur = 0;

  stageTile(0, 0);
  loadQ(qbA);
  for (int tkv = 0; tkv < ntA; ++tkv) {
    __syncthreads();
    if (tkv + 1 < ntA) stageTile(cur ^ 1, tkv + 1);
    else               stageTile(cur ^ 1, 0);
    computeTile(cur, qbA, tkv);
    cur ^= 1;
  }
  writeO(qbA);
  loadQ(qbB);
  for (int tkv = 0; tkv < ntB; ++tkv) {
    __syncthreads();
    if (tkv + 1 < ntB) stageTile(cur ^ 1, tkv + 1);
    computeTile(cur, qbB, tkv);
    cur ^= 1;
  }
  writeO(qbB);
}

extern "C" void kernel_launch(void* const* d_in, const int* in_sizes, int n_in,
                              void* d_out, int out_size, void* d_ws, size_t ws_size,
                              hipStream_t stream) {
  const float* x  = (const float*)d_in[0];
  const float* Wq = (const float*)d_in[1];
  const float* Wk = (const float*)d_in[2];
  const float* Wv = (const float*)d_in[3];
  const float* Wo = (const float*)d_in[4];
  char* p = (char*)d_ws;
  unsigned short* xb    = (unsigned short*)p;                 // 16 MB (reused as Ao)
  unsigned short* wqkvb = (unsigned short*)(p + 16777216);    // 24 MB
  unsigned short* wob   = (unsigned short*)(p + 41943040);    //  8 MB
  unsigned short* Qb    = (unsigned short*)(p + 50331648);    // 16 MB
  unsigned short* Kb    = (unsigned short*)(p + 67108864);    // 16 MB
  unsigned short* Vt    = (unsigned short*)(p + 83886080);    // 16 MB
  float* ctab           = (float*)(p + 100663296);            // 0.5 MB
  float* stab           = (float*)(p + 101187584);            // 0.5 MB -> end 101711872
  unsigned short* Ao = xb;  // xb dead after gemm_qkv

  cvt_all<<<dim3(4096, 5), 256, 0, stream>>>(x, Wq, Wk, Wv, Wo, xb, wqkvb, wob);
  rope_table<<<512, 256, 0, stream>>>(ctab, stab);
  gemm_dp<0><<<768, 512, 0, stream>>>(xb, wqkvb, Qb, Kb, Vt, 6144, 2048, 24);
  rope_apply<<<2048, 256, 0, stream>>>(Qb, Kb, ctab, stab);
  attn_fwd<<<dim3(16, 32), 256, 0, stream>>>(Qb, Kb, Vt, Ao);
  gemm_dp<1><<<256, 512, 0, stream>>>(Ao, wob, d_out, nullptr, nullptr, 2048, 2048, 8);
}